// Round 4
// baseline (280.619 us; speedup 1.0000x reference)
//
#include <hip/hip_runtime.h>
#include <hip/hip_bf16.h>
#include <math.h>

#define DIM  2048
#define NEXP 32
#define DFF  1024
#define NTOK 1024
#define TOPK 4
#define NGRP 4
#define EPG  8
#define SCALE 2.5f

#define BM 128
#define BN 64
#define BK 64
#define MAX_TILES 80
#define MAX_ROWS  10240   // 80 * 128

typedef unsigned int  uint_t;
typedef unsigned short us_t;

typedef __attribute__((ext_vector_type(8))) short bf16x8;
typedef __attribute__((ext_vector_type(4))) float f32x4;

// raw barrier: no implicit vmcnt(0) drain (keeps prefetch loads in flight),
// but LDS writes/reads must be complete before crossing (m201-proven pattern)
#define BARSYNC() do { asm volatile("s_waitcnt lgkmcnt(0)" ::: "memory"); \
                       __builtin_amdgcn_s_barrier(); } while (0)

__device__ inline us_t f2b(float f) {
  __hip_bfloat16 h = __float2bfloat16(f);   // RNE via v_cvt
  return *reinterpret_cast<const us_t*>(&h);
}

__device__ inline uint4 cvt8(float4 a, float4 b) {
  uint4 r;
  r.x = (uint_t)f2b(a.x) | ((uint_t)f2b(a.y) << 16);
  r.y = (uint_t)f2b(a.z) | ((uint_t)f2b(a.w) << 16);
  r.z = (uint_t)f2b(b.x) | ((uint_t)f2b(b.y) << 16);
  r.w = (uint_t)f2b(b.z) | ((uint_t)f2b(b.w) << 16);
  return r;
}

// ---------------- x -> bf16, also zeroes d_out (1 float4/thread) ----------------
__global__ __launch_bounds__(256) void xcast_kernel(const float4* __restrict__ x4,
                                                    uint2* __restrict__ xb4,
                                                    float4* __restrict__ out4) {
  int i = blockIdx.x * 256 + threadIdx.x;
  float4 v = x4[i];
  uint2 o;
  o.x = (uint_t)f2b(v.x) | ((uint_t)f2b(v.y) << 16);
  o.y = (uint_t)f2b(v.z) | ((uint_t)f2b(v.w) << 16);
  xb4[i] = o;
  out4[i] = make_float4(0.f, 0.f, 0.f, 0.f);   // 524288 threads == out_size/4
}

// ---------------- router ----------------
__global__ __launch_bounds__(64) void router_kernel(const float* __restrict__ x,
                                                    const float* __restrict__ gw,
                                                    const float* __restrict__ bias,
                                                    int* __restrict__ inds,
                                                    float* __restrict__ wts) {
  int t = blockIdx.x, l = threadIdx.x;
  float xr[32];
#pragma unroll
  for (int i = 0; i < 32; i++) xr[i] = x[t * DIM + i * 64 + l];
  __shared__ float lg[NEXP];
  for (int e = 0; e < NEXP; e++) {
    const float* w = gw + e * DIM;
    float acc = 0.f;
#pragma unroll
    for (int i = 0; i < 32; i++) acc += xr[i] * w[i * 64 + l];
#pragma unroll
    for (int off = 32; off > 0; off >>= 1) acc += __shfl_xor(acc, off);
    if (l == 0) lg[e] = acc;
  }
  __syncthreads();
  if (l != 0) return;

  float s[NEXP], sb[NEXP], mv[NEXP];
#pragma unroll
  for (int e = 0; e < NEXP; e++) {
    float sv = 1.f / (1.f + expf(-lg[e]));
    s[e] = sv; sb[e] = sv + bias[e];
  }
  float gs[NGRP];
#pragma unroll
  for (int g = 0; g < NGRP; g++) {
    float m1 = -1e30f, m2 = -1e30f;
#pragma unroll
    for (int j = 0; j < EPG; j++) {
      float v = sb[g * EPG + j];
      if (v > m1) { m2 = m1; m1 = v; } else if (v > m2) { m2 = v; }
    }
    gs[g] = m1 + m2;
  }
  int g1 = 0;
#pragma unroll
  for (int g = 1; g < NGRP; g++) if (gs[g] > gs[g1]) g1 = g;
  int g2 = -1; float g2v = -1e30f;
#pragma unroll
  for (int g = 0; g < NGRP; g++) {
    if (g == g1) continue;
    if (gs[g] > g2v) { g2v = gs[g]; g2 = g; }
  }
#pragma unroll
  for (int e = 0; e < NEXP; e++) {
    bool keep = (e == g1 * EPG) || (e == g2 * EPG);
    mv[e] = keep ? sb[e] : 0.f;
  }
  uint_t used = 0; float wsum = 0.f;
  int id[TOPK]; float wv[TOPK];
#pragma unroll
  for (int kk = 0; kk < TOPK; kk++) {
    float bv = -1e30f, bs = 0.f; int best = 0;
#pragma unroll
    for (int e = 0; e < NEXP; e++) {
      bool ok = !((used >> e) & 1u) && (mv[e] > bv);
      if (ok) { bv = mv[e]; best = e; bs = s[e]; }
    }
    used |= (1u << best);
    id[kk] = best; wv[kk] = bs; wsum += bs;
  }
  float inv = SCALE / (wsum + 1e-20f);
#pragma unroll
  for (int kk = 0; kk < TOPK; kk++) {
    inds[t * TOPK + kk] = id[kk];
    wts[t * TOPK + kk] = wv[kk] * inv;
  }
}

// ---------------- plan: stable compaction + 128-row tile descriptors ----------------
__global__ __launch_bounds__(256) void plan_kernel(const int* __restrict__ inds,
                                                   const float* __restrict__ wts,
                                                   int* __restrict__ row2tok,
                                                   float* __restrict__ roww,
                                                   int* __restrict__ tileE,
                                                   int* __restrict__ tileR,
                                                   int* __restrict__ nT) {
  __shared__ int wsum[4];
  __shared__ int s_off, s_nt;
  int tid = threadIdx.x, lane = tid & 63, wv = tid >> 6;
  if (tid == 0) { s_off = 0; s_nt = 0; }
  int tb = tid * 4;
  int myi[16];
#pragma unroll
  for (int j = 0; j < 4; j++)
#pragma unroll
    for (int k = 0; k < TOPK; k++) myi[j * 4 + k] = inds[(tb + j) * TOPK + k];
  __syncthreads();
  for (int e = 0; e < NEXP; e++) {
    int off0 = s_off;
    int slot[4]; int cnt = 0;
#pragma unroll
    for (int j = 0; j < 4; j++) {
      int sl = -1;
#pragma unroll
      for (int k = 0; k < TOPK; k++) if (myi[j * 4 + k] == e) sl = k;
      slot[j] = sl; cnt += (sl >= 0) ? 1 : 0;
    }
    int v = cnt;
#pragma unroll
    for (int off = 1; off < 64; off <<= 1) {
      int u = __shfl_up(v, (unsigned)off);
      if (lane >= off) v += u;
    }
    if (lane == 63) wsum[wv] = v;
    __syncthreads();
    int base = 0;
#pragma unroll
    for (int w = 0; w < 4; w++) base += (w < wv) ? wsum[w] : 0;
    int total = wsum[0] + wsum[1] + wsum[2] + wsum[3];
    int r = off0 + base + v - cnt;
#pragma unroll
    for (int j = 0; j < 4; j++) {
      if (slot[j] >= 0) {
        int t = tb + j;
        row2tok[r] = t; roww[r] = wts[t * TOPK + slot[j]];
        r++;
      }
    }
    int ntm = (total + BM - 1) / BM;
    int padEnd = off0 + ntm * BM;
    for (int q = off0 + total + tid; q < padEnd; q += 256) { row2tok[q] = 0; roww[q] = 0.f; }
    __syncthreads();
    if (tid == 0) {
      for (int i = 0; i < ntm; i++) { tileE[s_nt + i] = e; tileR[s_nt + i] = off0 + i * BM; }
      s_nt += ntm; s_off = padEnd;
    }
    __syncthreads();
  }
  int off0 = s_off;
  for (int t = tid; t < NTOK; t += 256) { row2tok[off0 + t] = t; roww[off0 + t] = 1.f; }
  if (tid == 0) {
    for (int i = 0; i < NTOK / BM; i++) { tileE[s_nt + i] = NEXP; tileR[s_nt + i] = off0 + i * BM; }
    nT[0] = s_nt + NTOK / BM;
  }
}

// ---------------- gate/up GEMM: 128x64 tiles, 8 waves, reg-prefetch pipeline ----------------
__global__ __launch_bounds__(512) void gateup_kernel(const us_t* __restrict__ xb,
                                                     const float* __restrict__ Wg,
                                                     const float* __restrict__ Wu,
                                                     const float* __restrict__ sWg,
                                                     const float* __restrict__ sWu,
                                                     const int* __restrict__ row2tok,
                                                     const int* __restrict__ tileE,
                                                     const int* __restrict__ tileR,
                                                     const int* __restrict__ nT,
                                                     us_t* __restrict__ H) {
  int hw = blockIdx.x;
  int work = (hw & 7) * (MAX_TILES * (DFF / BN) / 8) + (hw >> 3);
  int tile = work % MAX_TILES;
  int n0 = (work / MAX_TILES) * BN;
  if (tile >= nT[0]) return;
  int e = tileE[tile], row0 = tileR[tile];
  const float* wgp = (e < NEXP) ? (Wg + (size_t)e * DFF * DIM) : sWg;
  const float* wup = (e < NEXP) ? (Wu + (size_t)e * DFF * DIM) : sWu;

  __shared__ us_t Xs[BM][BK];
  __shared__ us_t Gs[BN][BK];
  __shared__ us_t Us[BN][BK];

  int tid = threadIdx.x;
  int lane = tid & 63;
  int wid = tid >> 6;
  int wm = (wid >> 1) * 32, wn = (wid & 1) * 32;

  int srow = tid >> 2;
  int c0 = (tid & 3) * 2;
  int scol = (tid & 3) * 16;
  int sw = srow & 7;
  int tok = row2tok[row0 + srow];
  const us_t* xrow = xb + (size_t)tok * DIM;
  int wr = tid >> 3;
  int wc = tid & 7;
  int wsw = wc ^ (wr & 7);
  const float* grow = wgp + (size_t)(n0 + wr) * DIM + wc * 8;
  const float* urow = wup + (size_t)(n0 + wr) * DIM + wc * 8;

  f32x4 accg[2][2] = {};
  f32x4 accu[2][2] = {};

  uint4 xr0, xr1; float4 gr0, gr1, ur0, ur1;   // current set
  uint4 xn0, xn1; float4 gn0, gn1, un0, un1;   // next set

#define GU_LOAD(KT, X0, X1, G0, G1, U0, U1) do {              \
    const uint4* xs_ = (const uint4*)(xrow + (KT) + scol);    \
    X0 = xs_[0]; X1 = xs_[1];                                 \
    const float4* gs_ = (const float4*)(grow + (KT));         \
    G0 = gs_[0]; G1 = gs_[1];                                 \
    const float4* us_ = (const float4*)(urow + (KT));         \
    U0 = us_[0]; U1 = us_[1];                                 \
  } while (0)

#define GU_STAGE(X0, X1, G0, G1, U0, U1) do {                 \
    uint4* dx_ = (uint4*)&Xs[srow][0];                        \
    dx_[c0 ^ sw] = X0; dx_[(c0 + 1) ^ sw] = X1;               \
    ((uint4*)&Gs[wr][0])[wsw] = cvt8(G0, G1);                 \
    ((uint4*)&Us[wr][0])[wsw] = cvt8(U0, U1);                 \
  } while (0)

  auto compute = [&]() {
#pragma unroll
    for (int ks = 0; ks < BK; ks += 32) {
      int cb = (ks >> 3) + (lane >> 4);
      bf16x8 af[2], bg[2], bu[2];
#pragma unroll
      for (int mi = 0; mi < 2; mi++) {
        int r = wm + mi * 16 + (lane & 15);
        af[mi] = *(const bf16x8*)&(((const uint4*)&Xs[r][0])[cb ^ (r & 7)]);
      }
#pragma unroll
      for (int ni = 0; ni < 2; ni++) {
        int r = wn + ni * 16 + (lane & 15);
        bg[ni] = *(const bf16x8*)&(((const uint4*)&Gs[r][0])[cb ^ (r & 7)]);
        bu[ni] = *(const bf16x8*)&(((const uint4*)&Us[r][0])[cb ^ (r & 7)]);
      }
#pragma unroll
      for (int mi = 0; mi < 2; mi++)
#pragma unroll
        for (int ni = 0; ni < 2; ni++) {
          accg[mi][ni] = __builtin_amdgcn_mfma_f32_16x16x32_bf16(af[mi], bg[ni], accg[mi][ni], 0, 0, 0);
          accu[mi][ni] = __builtin_amdgcn_mfma_f32_16x16x32_bf16(af[mi], bu[ni], accu[mi][ni], 0, 0, 0);
        }
    }
  };

  GU_LOAD(0, xr0, xr1, gr0, gr1, ur0, ur1);
  for (int kt = 0; kt < DIM; kt += 2 * BK) {
    GU_LOAD(kt + BK, xn0, xn1, gn0, gn1, un0, un1);
    GU_STAGE(xr0, xr1, gr0, gr1, ur0, ur1);
    BARSYNC();
    compute();
    BARSYNC();
    if (kt + 2 * BK < DIM) GU_LOAD(kt + 2 * BK, xr0, xr1, gr0, gr1, ur0, ur1);
    GU_STAGE(xn0, xn1, gn0, gn1, un0, un1);
    BARSYNC();
    compute();
    BARSYNC();
  }

#pragma unroll
  for (int mi = 0; mi < 2; mi++) {
#pragma unroll
    for (int j = 0; j < 4; j++) {
      int r = row0 + wm + mi * 16 + (lane >> 4) * 4 + j;
      us_t* hrow = H + (size_t)r * DFF;
#pragma unroll
      for (int ni = 0; ni < 2; ni++) {
        float g = accg[mi][ni][j], u = accu[mi][ni][j];
        float h = (g / (1.f + expf(-g))) * u;
        hrow[n0 + wn + ni * 16 + (lane & 15)] = f2b(h);
      }
    }
  }
}

// ---------------- down GEMM + weighted scatter-add, reg-prefetch pipeline ----------------
__global__ __launch_bounds__(512) void down_kernel(const us_t* __restrict__ H,
                                                   const float* __restrict__ Wd,
                                                   const float* __restrict__ sWd,
                                                   const int* __restrict__ row2tok,
                                                   const float* __restrict__ roww,
                                                   const int* __restrict__ tileE,
                                                   const int* __restrict__ tileR,
                                                   const int* __restrict__ nT,
                                                   float* __restrict__ out) {
  int hw = blockIdx.x;
  int work = (hw & 7) * (MAX_TILES * (DIM / BN) / 8) + (hw >> 3);
  int tile = work % MAX_TILES;
  int n0 = (work / MAX_TILES) * BN;
  if (tile >= nT[0]) return;
  int e = tileE[tile], row0 = tileR[tile];
  const float* wd = (e < NEXP) ? (Wd + (size_t)e * DIM * DFF) : sWd;

  __shared__ us_t Hs[BM][BK];
  __shared__ us_t Ds[BN][BK];

  int tid = threadIdx.x;
  int lane = tid & 63;
  int wid = tid >> 6;
  int wm = (wid >> 1) * 32, wn = (wid & 1) * 32;

  int srow = tid >> 2;
  int c0 = (tid & 3) * 2;
  int scol = (tid & 3) * 16;
  int sw = srow & 7;
  const us_t* hrow = H + (size_t)(row0 + srow) * DFF;
  int wr = tid >> 3;
  int wc = tid & 7;
  int wsw = wc ^ (wr & 7);
  const float* drow = wd + (size_t)(n0 + wr) * DFF + wc * 8;

  f32x4 acc[2][2] = {};

  uint4 hr0, hr1; float4 dr0, dr1;
  uint4 hn0, hn1; float4 dn0, dn1;

#define DN_LOAD(KT, H0, H1, D0, D1) do {                      \
    const uint4* hs_ = (const uint4*)(hrow + (KT) + scol);    \
    H0 = hs_[0]; H1 = hs_[1];                                 \
    const float4* ds_ = (const float4*)(drow + (KT));         \
    D0 = ds_[0]; D1 = ds_[1];                                 \
  } while (0)

#define DN_STAGE(H0, H1, D0, D1) do {                         \
    uint4* dh_ = (uint4*)&Hs[srow][0];                        \
    dh_[c0 ^ sw] = H0; dh_[(c0 + 1) ^ sw] = H1;               \
    ((uint4*)&Ds[wr][0])[wsw] = cvt8(D0, D1);                 \
  } while (0)

  auto compute = [&]() {
#pragma unroll
    for (int ks = 0; ks < BK; ks += 32) {
      int cb = (ks >> 3) + (lane >> 4);
      bf16x8 af[2], bw[2];
#pragma unroll
      for (int mi = 0; mi < 2; mi++) {
        int r = wm + mi * 16 + (lane & 15);
        af[mi] = *(const bf16x8*)&(((const uint4*)&Hs[r][0])[cb ^ (r & 7)]);
      }
#pragma unroll
      for (int ni = 0; ni < 2; ni++) {
        int r = wn + ni * 16 + (lane & 15);
        bw[ni] = *(const bf16x8*)&(((const uint4*)&Ds[r][0])[cb ^ (r & 7)]);
      }
#pragma unroll
      for (int mi = 0; mi < 2; mi++)
#pragma unroll
        for (int ni = 0; ni < 2; ni++)
          acc[mi][ni] = __builtin_amdgcn_mfma_f32_16x16x32_bf16(af[mi], bw[ni], acc[mi][ni], 0, 0, 0);
    }
  };

  DN_LOAD(0, hr0, hr1, dr0, dr1);
  for (int kt = 0; kt < DFF; kt += 2 * BK) {
    DN_LOAD(kt + BK, hn0, hn1, dn0, dn1);
    DN_STAGE(hr0, hr1, dr0, dr1);
    BARSYNC();
    compute();
    BARSYNC();
    if (kt + 2 * BK < DFF) DN_LOAD(kt + 2 * BK, hr0, hr1, dr0, dr1);
    DN_STAGE(hn0, hn1, dn0, dn1);
    BARSYNC();
    compute();
    BARSYNC();
  }

#pragma unroll
  for (int mi = 0; mi < 2; mi++) {
#pragma unroll
    for (int j = 0; j < 4; j++) {
      int r = row0 + wm + mi * 16 + (lane >> 4) * 4 + j;
      float wgt = roww[r];
      int tok = row2tok[r];
      float* orow = out + (size_t)tok * DIM;
#pragma unroll
      for (int ni = 0; ni < 2; ni++)
        atomicAdd(orow + n0 + wn + ni * 16 + (lane & 15), acc[mi][ni][j] * wgt);
    }
  }
}

extern "C" void kernel_launch(void* const* d_in, const int* in_sizes, int n_in,
                              void* d_out, int out_size, void* d_ws, size_t ws_size,
                              hipStream_t stream) {
  const float* x    = (const float*)d_in[0];
  const float* gw   = (const float*)d_in[1];
  const float* bias = (const float*)d_in[2];
  const float* Wg   = (const float*)d_in[3];
  const float* Wu   = (const float*)d_in[4];
  const float* Wd   = (const float*)d_in[5];
  const float* sWg  = (const float*)d_in[6];
  const float* sWu  = (const float*)d_in[7];
  const float* sWd  = (const float*)d_in[8];
  float* out = (float*)d_out;

  char* p = (char*)d_ws;
  us_t* xb = (us_t*)p;            p += (size_t)NTOK * DIM * 2;
  us_t* H  = (us_t*)p;            p += (size_t)MAX_ROWS * DFF * 2;
  int* inds = (int*)p;            p += NTOK * TOPK * 4;
  float* wts = (float*)p;         p += NTOK * TOPK * 4;
  int* row2tok = (int*)p;         p += MAX_ROWS * 4;
  float* roww = (float*)p;        p += MAX_ROWS * 4;
  int* tileE = (int*)p;           p += MAX_TILES * 4;
  int* tileR = (int*)p;           p += MAX_TILES * 4;
  int* nT = (int*)p;              p += 4;

  hipLaunchKernelGGL(xcast_kernel, dim3(NTOK * DIM / 1024), dim3(256), 0, stream,
                     (const float4*)x, (uint2*)xb, (float4*)out);
  hipLaunchKernelGGL(router_kernel, dim3(NTOK), dim3(64), 0, stream, x, gw, bias, inds, wts);
  hipLaunchKernelGGL(plan_kernel, dim3(1), dim3(256), 0, stream,
                     inds, wts, row2tok, roww, tileE, tileR, nT);
  hipLaunchKernelGGL(gateup_kernel, dim3(MAX_TILES * (DFF / BN)), dim3(512), 0, stream,
                     xb, Wg, Wu, sWg, sWu, row2tok, tileE, tileR, nT, H);
  hipLaunchKernelGGL(down_kernel, dim3(MAX_TILES * (DIM / BN)), dim3(512), 0, stream,
                     H, Wd, sWd, row2tok, roww, tileE, tileR, nT, out);
}

// Round 5
// 244.050 us; speedup vs baseline: 1.1498x; 1.1498x over previous
//
#include <hip/hip_runtime.h>
#include <hip/hip_bf16.h>
#include <math.h>

#define DIM  2048
#define NEXP 32
#define DFF  1024
#define NTOK 1024
#define TOPK 4
#define NGRP 4
#define EPG  8
#define SCALE 2.5f

#define BM 128
#define BN 128
#define BK 64
#define MAX_TILES 80
#define MAX_ROWS  10240   // >= 4096 + 32*127 + 1024

typedef unsigned int  uint_t;
typedef unsigned short us_t;

typedef __attribute__((ext_vector_type(8))) short bf16x8;
typedef __attribute__((ext_vector_type(4))) float f32x4;

// async global->LDS, 16B per lane; LDS dst = wave-uniform base + lane*16
#define GLOAD_LDS16(g, l) __builtin_amdgcn_global_load_lds( \
    (const __attribute__((address_space(1))) unsigned int*)(g), \
    (__attribute__((address_space(3))) unsigned int*)(l), 16, 0, 0)

__device__ inline us_t f2b(float f) {
  __hip_bfloat16 h = __float2bfloat16(f);   // RNE via v_cvt
  return *reinterpret_cast<const us_t*>(&h);
}

__device__ inline uint4 cvt8(float4 a, float4 b) {
  uint4 r;
  r.x = (uint_t)f2b(a.x) | ((uint_t)f2b(a.y) << 16);
  r.y = (uint_t)f2b(a.z) | ((uint_t)f2b(a.w) << 16);
  r.z = (uint_t)f2b(b.x) | ((uint_t)f2b(b.y) << 16);
  r.w = (uint_t)f2b(b.z) | ((uint_t)f2b(b.w) << 16);
  return r;
}

// ---------------- x -> bf16, also zeroes d_out ----------------
__global__ __launch_bounds__(256) void xcast_kernel(const float4* __restrict__ x4,
                                                    uint2* __restrict__ xb4,
                                                    float4* __restrict__ out4) {
  int i = blockIdx.x * 256 + threadIdx.x;
  float4 v = x4[i];
  uint2 o;
  o.x = (uint_t)f2b(v.x) | ((uint_t)f2b(v.y) << 16);
  o.y = (uint_t)f2b(v.z) | ((uint_t)f2b(v.w) << 16);
  xb4[i] = o;
  out4[i] = make_float4(0.f, 0.f, 0.f, 0.f);
}

// ---------------- router ----------------
__global__ __launch_bounds__(64) void router_kernel(const float* __restrict__ x,
                                                    const float* __restrict__ gw,
                                                    const float* __restrict__ bias,
                                                    int* __restrict__ inds,
                                                    float* __restrict__ wts) {
  int t = blockIdx.x, l = threadIdx.x;
  float xr[32];
#pragma unroll
  for (int i = 0; i < 32; i++) xr[i] = x[t * DIM + i * 64 + l];
  __shared__ float lg[NEXP];
  for (int e = 0; e < NEXP; e++) {
    const float* w = gw + e * DIM;
    float acc = 0.f;
#pragma unroll
    for (int i = 0; i < 32; i++) acc += xr[i] * w[i * 64 + l];
#pragma unroll
    for (int off = 32; off > 0; off >>= 1) acc += __shfl_xor(acc, off);
    if (l == 0) lg[e] = acc;
  }
  __syncthreads();
  if (l != 0) return;

  float s[NEXP], sb[NEXP], mv[NEXP];
#pragma unroll
  for (int e = 0; e < NEXP; e++) {
    float sv = 1.f / (1.f + expf(-lg[e]));
    s[e] = sv; sb[e] = sv + bias[e];
  }
  float gs[NGRP];
#pragma unroll
  for (int g = 0; g < NGRP; g++) {
    float m1 = -1e30f, m2 = -1e30f;
#pragma unroll
    for (int j = 0; j < EPG; j++) {
      float v = sb[g * EPG + j];
      if (v > m1) { m2 = m1; m1 = v; } else if (v > m2) { m2 = v; }
    }
    gs[g] = m1 + m2;
  }
  int g1 = 0;
#pragma unroll
  for (int g = 1; g < NGRP; g++) if (gs[g] > gs[g1]) g1 = g;
  int g2 = -1; float g2v = -1e30f;
#pragma unroll
  for (int g = 0; g < NGRP; g++) {
    if (g == g1) continue;
    if (gs[g] > g2v) { g2v = gs[g]; g2 = g; }
  }
#pragma unroll
  for (int e = 0; e < NEXP; e++) {
    bool keep = (e == g1 * EPG) || (e == g2 * EPG);
    mv[e] = keep ? sb[e] : 0.f;
  }
  uint_t used = 0; float wsum = 0.f;
  int id[TOPK]; float wv[TOPK];
#pragma unroll
  for (int kk = 0; kk < TOPK; kk++) {
    float bv = -1e30f, bs = 0.f; int best = 0;
#pragma unroll
    for (int e = 0; e < NEXP; e++) {
      bool ok = !((used >> e) & 1u) && (mv[e] > bv);
      if (ok) { bv = mv[e]; best = e; bs = s[e]; }
    }
    used |= (1u << best);
    id[kk] = best; wv[kk] = bs; wsum += bs;
  }
  float inv = SCALE / (wsum + 1e-20f);
#pragma unroll
  for (int kk = 0; kk < TOPK; kk++) {
    inds[t * TOPK + kk] = id[kk];
    wts[t * TOPK + kk] = wv[kk] * inv;
  }
}

// ---------------- plan: stable compaction + 128-row tile descriptors ----------------
__global__ __launch_bounds__(256) void plan_kernel(const int* __restrict__ inds,
                                                   const float* __restrict__ wts,
                                                   int* __restrict__ row2tok,
                                                   float* __restrict__ roww,
                                                   int* __restrict__ tileE,
                                                   int* __restrict__ tileR,
                                                   int* __restrict__ nT) {
  __shared__ int wsum[4];
  __shared__ int s_off, s_nt;
  int tid = threadIdx.x, lane = tid & 63, wv = tid >> 6;
  if (tid == 0) { s_off = 0; s_nt = 0; }
  int tb = tid * 4;
  int myi[16];
#pragma unroll
  for (int j = 0; j < 4; j++)
#pragma unroll
    for (int k = 0; k < TOPK; k++) myi[j * 4 + k] = inds[(tb + j) * TOPK + k];
  __syncthreads();
  for (int e = 0; e < NEXP; e++) {
    int off0 = s_off;
    int slot[4]; int cnt = 0;
#pragma unroll
    for (int j = 0; j < 4; j++) {
      int sl = -1;
#pragma unroll
      for (int k = 0; k < TOPK; k++) if (myi[j * 4 + k] == e) sl = k;
      slot[j] = sl; cnt += (sl >= 0) ? 1 : 0;
    }
    int v = cnt;
#pragma unroll
    for (int off = 1; off < 64; off <<= 1) {
      int u = __shfl_up(v, (unsigned)off);
      if (lane >= off) v += u;
    }
    if (lane == 63) wsum[wv] = v;
    __syncthreads();
    int base = 0;
#pragma unroll
    for (int w = 0; w < 4; w++) base += (w < wv) ? wsum[w] : 0;
    int total = wsum[0] + wsum[1] + wsum[2] + wsum[3];
    int r = off0 + base + v - cnt;
#pragma unroll
    for (int j = 0; j < 4; j++) {
      if (slot[j] >= 0) {
        int t = tb + j;
        row2tok[r] = t; roww[r] = wts[t * TOPK + slot[j]];
        r++;
      }
    }
    int ntm = (total + BM - 1) / BM;
    int padEnd = off0 + ntm * BM;
    for (int q = off0 + total + tid; q < padEnd; q += 256) { row2tok[q] = 0; roww[q] = 0.f; }
    __syncthreads();
    if (tid == 0) {
      for (int i = 0; i < ntm; i++) { tileE[s_nt + i] = e; tileR[s_nt + i] = off0 + i * BM; }
      s_nt += ntm; s_off = padEnd;
    }
    __syncthreads();
  }
  int off0 = s_off;
  for (int t = tid; t < NTOK; t += 256) { row2tok[off0 + t] = t; roww[off0 + t] = 1.f; }
  if (tid == 0) {
    for (int i = 0; i < NTOK / BM; i++) { tileE[s_nt + i] = NEXP; tileR[s_nt + i] = off0 + i * BM; }
    nT[0] = s_nt + NTOK / BM;
  }
}

// ---------------- gate/up GEMM: 128x128 tiles, 8 waves (2x4), gload_lds X ----------------
__global__ __launch_bounds__(512) void gateup_kernel(const us_t* __restrict__ xb,
                                                     const float* __restrict__ Wg,
                                                     const float* __restrict__ Wu,
                                                     const float* __restrict__ sWg,
                                                     const float* __restrict__ sWu,
                                                     const int* __restrict__ row2tok,
                                                     const int* __restrict__ tileE,
                                                     const int* __restrict__ tileR,
                                                     const int* __restrict__ nT,
                                                     us_t* __restrict__ H) {
  int hw = blockIdx.x;                                   // 640 blocks, 640%8==0
  int work = (hw & 7) * (MAX_TILES * (DFF / BN) / 8) + (hw >> 3);
  int tile = work % MAX_TILES;
  int n0 = (work / MAX_TILES) * BN;
  if (tile >= nT[0]) return;
  int e = tileE[tile], row0 = tileR[tile];
  const float* wgp = (e < NEXP) ? (Wg + (size_t)e * DFF * DIM) : sWg;
  const float* wup = (e < NEXP) ? (Wu + (size_t)e * DFF * DIM) : sWu;

  __shared__ us_t Xs[BM][BK];   // 16 KB, content swizzled: slot(r,cc) = src chunk (r, cc^(r&7))
  __shared__ us_t Gs[BN][BK];   // 16 KB
  __shared__ us_t Us[BN][BK];   // 16 KB

  int tid = threadIdx.x;
  int lane = tid & 63;
  int wid = tid >> 6;
  int wmr = (wid >> 2) * 64;    // wave M origin (2 wave-rows)
  int wnc = (wid & 3) * 32;     // wave N origin (4 wave-cols)

  // --- X staging via global_load_lds: 1024 slots, wave w covers [w*128, w*128+128) ---
  int s0 = wid * 128 + lane, s1 = s0 + 64;
  int xr0 = s0 >> 3, xc0 = s0 & 7;
  int xr1 = s1 >> 3, xc1 = s1 & 7;
  const us_t* xsrc0 = xb + (size_t)row2tok[row0 + xr0] * DIM + (xc0 ^ (xr0 & 7)) * 8;
  const us_t* xsrc1 = xb + (size_t)row2tok[row0 + xr1] * DIM + (xc1 ^ (xr1 & 7)) * 8;
  us_t* xdst0 = &Xs[0][0] + (size_t)(wid * 128) * 8;    // slot*8 us_t = slot*16 bytes
  us_t* xdst1 = xdst0 + 64 * 8;

  // --- weight staging (fp32->bf16), slots tid and tid+512 per matrix ---
  int a0 = tid, a1 = tid + 512;
  int ar0 = a0 >> 3, ac0 = a0 & 7;
  int ar1 = a1 >> 3, ac1 = a1 & 7;
  const float* gsrc0 = wgp + (size_t)(n0 + ar0) * DIM + (ac0 ^ (ar0 & 7)) * 8;
  const float* gsrc1 = wgp + (size_t)(n0 + ar1) * DIM + (ac1 ^ (ar1 & 7)) * 8;
  const float* usrc0 = wup + (size_t)(n0 + ar0) * DIM + (ac0 ^ (ar0 & 7)) * 8;
  const float* usrc1 = wup + (size_t)(n0 + ar1) * DIM + (ac1 ^ (ar1 & 7)) * 8;
  uint4* gdst0 = (uint4*)((char*)&Gs[0][0] + (size_t)a0 * 16);
  uint4* gdst1 = (uint4*)((char*)&Gs[0][0] + (size_t)a1 * 16);
  uint4* udst0 = (uint4*)((char*)&Us[0][0] + (size_t)a0 * 16);
  uint4* udst1 = (uint4*)((char*)&Us[0][0] + (size_t)a1 * 16);

  f32x4 accg[4][2] = {};
  f32x4 accu[4][2] = {};

  for (int kt = 0; kt < DIM; kt += BK) {
    GLOAD_LDS16(xsrc0 + kt, xdst0);
    GLOAD_LDS16(xsrc1 + kt, xdst1);
    {
      const float4* p = (const float4*)(gsrc0 + kt); *gdst0 = cvt8(p[0], p[1]);
      p = (const float4*)(gsrc1 + kt);               *gdst1 = cvt8(p[0], p[1]);
      p = (const float4*)(usrc0 + kt);               *udst0 = cvt8(p[0], p[1]);
      p = (const float4*)(usrc1 + kt);               *udst1 = cvt8(p[0], p[1]);
    }
    __syncthreads();
#pragma unroll
    for (int ks = 0; ks < BK; ks += 32) {
      int cb = (ks >> 3) + (lane >> 4);
      bf16x8 af[4], bg[2], bu[2];
#pragma unroll
      for (int mi = 0; mi < 4; mi++) {
        int r = wmr + mi * 16 + (lane & 15);
        af[mi] = *(const bf16x8*)&(((const uint4*)&Xs[r][0])[cb ^ (r & 7)]);
      }
#pragma unroll
      for (int ni = 0; ni < 2; ni++) {
        int r = wnc + ni * 16 + (lane & 15);
        bg[ni] = *(const bf16x8*)&(((const uint4*)&Gs[r][0])[cb ^ (r & 7)]);
        bu[ni] = *(const bf16x8*)&(((const uint4*)&Us[r][0])[cb ^ (r & 7)]);
      }
#pragma unroll
      for (int mi = 0; mi < 4; mi++)
#pragma unroll
        for (int ni = 0; ni < 2; ni++) {
          accg[mi][ni] = __builtin_amdgcn_mfma_f32_16x16x32_bf16(af[mi], bg[ni], accg[mi][ni], 0, 0, 0);
          accu[mi][ni] = __builtin_amdgcn_mfma_f32_16x16x32_bf16(af[mi], bu[ni], accu[mi][ni], 0, 0, 0);
        }
    }
    __syncthreads();
  }
#pragma unroll
  for (int mi = 0; mi < 4; mi++) {
#pragma unroll
    for (int j = 0; j < 4; j++) {
      int r = row0 + wmr + mi * 16 + (lane >> 4) * 4 + j;
      us_t* hrow = H + (size_t)r * DFF;
#pragma unroll
      for (int ni = 0; ni < 2; ni++) {
        float g = accg[mi][ni][j], u = accu[mi][ni][j];
        float h = (g / (1.f + expf(-g))) * u;
        hrow[n0 + wnc + ni * 16 + (lane & 15)] = f2b(h);
      }
    }
  }
}

// ---------------- down GEMM + weighted scatter-add: 128x128 tiles ----------------
__global__ __launch_bounds__(512) void down_kernel(const us_t* __restrict__ H,
                                                   const float* __restrict__ Wd,
                                                   const float* __restrict__ sWd,
                                                   const int* __restrict__ row2tok,
                                                   const float* __restrict__ roww,
                                                   const int* __restrict__ tileE,
                                                   const int* __restrict__ tileR,
                                                   const int* __restrict__ nT,
                                                   float* __restrict__ out) {
  int hw = blockIdx.x;                                   // 1280 blocks
  int work = (hw & 7) * (MAX_TILES * (DIM / BN) / 8) + (hw >> 3);
  int tile = work % MAX_TILES;
  int n0 = (work / MAX_TILES) * BN;
  if (tile >= nT[0]) return;
  int e = tileE[tile], row0 = tileR[tile];
  const float* wd = (e < NEXP) ? (Wd + (size_t)e * DIM * DFF) : sWd;

  __shared__ us_t Hs[BM][BK];   // 16 KB
  __shared__ us_t Ds[BN][BK];   // 16 KB

  int tid = threadIdx.x;
  int lane = tid & 63;
  int wid = tid >> 6;
  int wmr = (wid >> 2) * 64;
  int wnc = (wid & 3) * 32;

  int s0 = wid * 128 + lane, s1 = s0 + 64;
  int hr0 = s0 >> 3, hc0 = s0 & 7;
  int hr1 = s1 >> 3, hc1 = s1 & 7;
  const us_t* hsrc0 = H + (size_t)(row0 + hr0) * DFF + (hc0 ^ (hr0 & 7)) * 8;
  const us_t* hsrc1 = H + (size_t)(row0 + hr1) * DFF + (hc1 ^ (hr1 & 7)) * 8;
  us_t* hdst0 = &Hs[0][0] + (size_t)(wid * 128) * 8;
  us_t* hdst1 = hdst0 + 64 * 8;

  int a0 = tid, a1 = tid + 512;
  int ar0 = a0 >> 3, ac0 = a0 & 7;
  int ar1 = a1 >> 3, ac1 = a1 & 7;
  const float* dsrc0 = wd + (size_t)(n0 + ar0) * DFF + (ac0 ^ (ar0 & 7)) * 8;
  const float* dsrc1 = wd + (size_t)(n0 + ar1) * DFF + (ac1 ^ (ar1 & 7)) * 8;
  uint4* ddst0 = (uint4*)((char*)&Ds[0][0] + (size_t)a0 * 16);
  uint4* ddst1 = (uint4*)((char*)&Ds[0][0] + (size_t)a1 * 16);

  f32x4 acc[4][2] = {};

  for (int kt = 0; kt < DFF; kt += BK) {
    GLOAD_LDS16(hsrc0 + kt, hdst0);
    GLOAD_LDS16(hsrc1 + kt, hdst1);
    {
      const float4* p = (const float4*)(dsrc0 + kt); *ddst0 = cvt8(p[0], p[1]);
      p = (const float4*)(dsrc1 + kt);               *ddst1 = cvt8(p[0], p[1]);
    }
    __syncthreads();
#pragma unroll
    for (int ks = 0; ks < BK; ks += 32) {
      int cb = (ks >> 3) + (lane >> 4);
      bf16x8 af[4], bw[2];
#pragma unroll
      for (int mi = 0; mi < 4; mi++) {
        int r = wmr + mi * 16 + (lane & 15);
        af[mi] = *(const bf16x8*)&(((const uint4*)&Hs[r][0])[cb ^ (r & 7)]);
      }
#pragma unroll
      for (int ni = 0; ni < 2; ni++) {
        int r = wnc + ni * 16 + (lane & 15);
        bw[ni] = *(const bf16x8*)&(((const uint4*)&Ds[r][0])[cb ^ (r & 7)]);
      }
#pragma unroll
      for (int mi = 0; mi < 4; mi++)
#pragma unroll
        for (int ni = 0; ni < 2; ni++)
          acc[mi][ni] = __builtin_amdgcn_mfma_f32_16x16x32_bf16(af[mi], bw[ni], acc[mi][ni], 0, 0, 0);
    }
    __syncthreads();
  }
#pragma unroll
  for (int mi = 0; mi < 4; mi++) {
#pragma unroll
    for (int j = 0; j < 4; j++) {
      int r = row0 + wmr + mi * 16 + (lane >> 4) * 4 + j;
      float wgt = roww[r];
      int tok = row2tok[r];
      float* orow = out + (size_t)tok * DIM;
#pragma unroll
      for (int ni = 0; ni < 2; ni++)
        atomicAdd(orow + n0 + wnc + ni * 16 + (lane & 15), acc[mi][ni][j] * wgt);
    }
  }
}

extern "C" void kernel_launch(void* const* d_in, const int* in_sizes, int n_in,
                              void* d_out, int out_size, void* d_ws, size_t ws_size,
                              hipStream_t stream) {
  const float* x    = (const float*)d_in[0];
  const float* gw   = (const float*)d_in[1];
  const float* bias = (const float*)d_in[2];
  const float* Wg   = (const float*)d_in[3];
  const float* Wu   = (const float*)d_in[4];
  const float* Wd   = (const float*)d_in[5];
  const float* sWg  = (const float*)d_in[6];
  const float* sWu  = (const float*)d_in[7];
  const float* sWd  = (const float*)d_in[8];
  float* out = (float*)d_out;

  char* p = (char*)d_ws;
  us_t* xb = (us_t*)p;            p += (size_t)NTOK * DIM * 2;
  us_t* H  = (us_t*)p;            p += (size_t)MAX_ROWS * DFF * 2;
  int* inds = (int*)p;            p += NTOK * TOPK * 4;
  float* wts = (float*)p;         p += NTOK * TOPK * 4;
  int* row2tok = (int*)p;         p += MAX_ROWS * 4;
  float* roww = (float*)p;        p += MAX_ROWS * 4;
  int* tileE = (int*)p;           p += MAX_TILES * 4;
  int* tileR = (int*)p;           p += MAX_TILES * 4;
  int* nT = (int*)p;              p += 4;

  hipLaunchKernelGGL(xcast_kernel, dim3(NTOK * DIM / 1024), dim3(256), 0, stream,
                     (const float4*)x, (uint2*)xb, (float4*)out);
  hipLaunchKernelGGL(router_kernel, dim3(NTOK), dim3(64), 0, stream, x, gw, bias, inds, wts);
  hipLaunchKernelGGL(plan_kernel, dim3(1), dim3(256), 0, stream,
                     inds, wts, row2tok, roww, tileE, tileR, nT);
  hipLaunchKernelGGL(gateup_kernel, dim3(MAX_TILES * (DFF / BN)), dim3(512), 0, stream,
                     xb, Wg, Wu, sWg, sWu, row2tok, tileE, tileR, nT, H);
  hipLaunchKernelGGL(down_kernel, dim3(MAX_TILES * (DIM / BN)), dim3(512), 0, stream,
                     H, Wd, sWd, row2tok, roww, tileE, tileR, nT, out);
}